// Round 10
// baseline (297.005 us; speedup 1.0000x reference)
//
#include <hip/hip_runtime.h>
#include <hip/hip_bf16.h>
#include <hip/hip_fp16.h>

#define NN 50000      // nodes
#define NE 1600000    // edges
#define DD 128        // channels
#define HH 4          // heads
#define BSH2 5        // bucket shift: 32 nodes per bucket
#define NBKT2 1563    // ceil(NN / 32)
#define NBP2 2048     // padded bucket count
#define CAP 1408      // padded edges per bucket (mean 1024, +12 sigma)
#define PCHUNK 8192   // edges per partition chunk
#define NPB 196       // ceil(NE / PCHUNK)
#define WSB 192       // weight-split role blocks (49152 / 256)
#define NGB2 391      // gemm blocks: ceil(3125 tiles / 8 waves)

typedef __attribute__((ext_vector_type(8))) short short8;
typedef __attribute__((ext_vector_type(4))) float floatx4;
typedef __attribute__((ext_vector_type(2))) _Float16 h2;

__device__ inline h2 as_h2(unsigned u) {
    union { unsigned u; h2 h; } c; c.u = u; return c.h;
}

__device__ inline float dot4(h2 a01, h2 a23, h2 b01, h2 b23) {
#if defined(__has_builtin) && __has_builtin(__builtin_amdgcn_fdot2)
    return __builtin_amdgcn_fdot2(a01, b01, __builtin_amdgcn_fdot2(a23, b23, 0.f, false), false);
#else
    return (float)a01.x * (float)b01.x + (float)a01.y * (float)b01.y +
           (float)a23.x * (float)b23.x + (float)a23.y * (float)b23.y;
#endif
}

// ---------------- part_prep: partition role [0,NPB) + weight-split role [NPB,NPB+WSB) ----------------
// Partition: two-level bucket-window scatter (measured-cheap): LDS histogram, ONE aggregated
// global atomic per nonzero bucket (~300K over 2048 addrs), then scatter into bucket windows.
__global__ __launch_bounds__(256) void part_prep(
    const float* __restrict__ Wk, const float* __restrict__ Wq, const float* __restrict__ Wv,
    unsigned short* __restrict__ hi, unsigned short* __restrict__ lo,
    const int* __restrict__ src, const int* __restrict__ dst,
    int* __restrict__ bcur, int* __restrict__ epack)
{
    __shared__ int h[NBP2];
    __shared__ int c2[NBP2];
    if (blockIdx.x >= NPB) {
        int j = (blockIdx.x - NPB) * 256 + threadIdx.x;      // j < 49152 always
        int which = j / (DD * DD);
        int off = j - which * (DD * DD);
        const float* W = (which == 0) ? Wk : (which == 1) ? Wq : Wv;
        float w = W[off];
        unsigned int b = __float_as_uint(w);
        unsigned short hh = (unsigned short)(b >> 16);
        float hf = __uint_as_float((unsigned int)hh << 16);
        float l = w - hf;
        hi[j] = hh;
        lo[j] = (unsigned short)(__float_as_uint(l) >> 16);
        return;
    }
    int pb = blockIdx.x;
    int b0 = pb * PCHUNK;
    int n = min(PCHUNK, NE - b0);
    for (int i = threadIdx.x; i < NBP2; i += 256) h[i] = 0;
    __syncthreads();
    for (int i = threadIdx.x; i < n; i += 256)
        atomicAdd(&h[dst[b0 + i] >> BSH2], 1);
    __syncthreads();
    for (int i = threadIdx.x; i < NBP2; i += 256)
        c2[i] = h[i] ? i * CAP + atomicAdd(&bcur[i], h[i]) : 0;
    __syncthreads();
    for (int i = threadIdx.x; i < n; i += 256) {
        int d = dst[b0 + i];
        int s = src[b0 + i];
        int bkt = d >> BSH2;
        int pos = atomicAdd(&c2[bkt], 1);
        if (pos < (bkt + 1) * CAP)               // drop-guard (never fires at +12 sigma)
            epack[pos] = ((d & 31) << 16) | s;
    }
}

// ---------------- gemm: SINGLE-PASS fused QKV projection ----------------
// All three hi-matrices staged in LDS (96 KB, XOR-swizzled vs the 16-slot bank conflict);
// lo streamed from L2 (measured-free, R3 vs R5). 512-thread blocks: stage 32 KB -> 128 KB LDS,
// 1 block/CU, 8 waves/CU (same occupancy as the 3-pass design). Each wave owns ONE 16-row
// x-tile: load + bf16-split ONCE, then K/V/Q back-to-back (96 MFMAs, 24 independent acc
// chains in one scheduling window vs 8 in the 3-pass version; 1/3 the x-loads and splits).
__global__ __launch_bounds__(512) void gemm(
    const float* __restrict__ x,
    const unsigned short* __restrict__ whi, const unsigned short* __restrict__ wlo,
    const float* __restrict__ bk, const float* __restrict__ bq, const float* __restrict__ bv,
    uint2* __restrict__ kv2, uint4* __restrict__ qh4)
{
    __shared__ __align__(16) unsigned char smem[131072]; // [0,96K) 3x hi-swz; [96K,128K) stage

    uint4* wh4 = (uint4*)smem;
    int tid = threadIdx.x;
    int wave = tid >> 6, lane = tid & 63;
    int m = lane & 15, quad = lane >> 4;
    unsigned short* st = (unsigned short*)(smem + 98304 + wave * 4096);
    uint4* st4 = (uint4*)st;
    uint2* st2 = (uint2*)st;

    // stage all 3 hi matrices, swizzled: uint4 g (within matrix) -> slot (g&~15)|((g^(g>>4))&15)
    const uint4* gh = (const uint4*)whi;
    for (int idx = tid; idx < 3 * 2048; idx += 512) {
        int wm = idx >> 11, g = idx & 2047;
        int l = (g & ~15) | ((g ^ (g >> 4)) & 15);
        wh4[wm * 2048 + l] = gh[idx];
    }
    __syncthreads();

    int tile = blockIdx.x * 8 + wave;
    if (tile >= 3125) return;
    int n0 = tile * 16;

    // load + split this wave's 16-row x-tile ONCE
    const float* xrow = x + (size_t)(n0 + m) * DD + quad * 8;
    short8 ah[4], al[4];
#pragma unroll
    for (int ks = 0; ks < 4; ++ks) {
        const float* xr = xrow + ks * 32;
        float4 t0 = *(const float4*)xr;
        float4 t1 = *(const float4*)(xr + 4);
        float xv[8] = {t0.x, t0.y, t0.z, t0.w, t1.x, t1.y, t1.z, t1.w};
#pragma unroll
        for (int j = 0; j < 8; ++j) {
            unsigned int b = __float_as_uint(xv[j]);
            unsigned short h = (unsigned short)(b >> 16);
            float hf = __uint_as_float((unsigned int)h << 16);
            float l = xv[j] - hf;
            ah[ks][j] = (short)h;
            al[ks][j] = (short)(__float_as_uint(l) >> 16);
        }
    }

    // K, V, Q back-to-back on the same x fragments
    for (int pp = 0; pp < 3; ++pp) {
        int wm = (pp == 0) ? 0 : (pp == 1) ? 2 : 1;          // matrix index: K=0, V=2, Q=1
        const unsigned short* wloP = wlo + (size_t)wm * (DD * DD);
        const short8* whP = (const short8*)(wh4 + wm * 2048);
        const float* bias = (pp == 0) ? bk : (pp == 1) ? bv : bq;
        float bs[8];
#pragma unroll
        for (int ct = 0; ct < 8; ++ct) bs[ct] = bias[ct * 16 + m];

        floatx4 acc[8];
#pragma unroll
        for (int ct = 0; ct < 8; ++ct) acc[ct] = (floatx4){0.f, 0.f, 0.f, 0.f};

#pragma unroll
        for (int ks = 0; ks < 4; ++ks) {
#pragma unroll
            for (int ct = 0; ct < 8; ++ct) {
                int r = ct * 16 + m;                         // output channel; r&15 == m
                short8 bh = whP[r * 16 + ((ks * 4 + quad) ^ m)];
                short8 bl = *(const short8*)(wloP + (size_t)r * 128 + ks * 32 + quad * 8);
                acc[ct] = __builtin_amdgcn_mfma_f32_16x16x32_bf16(ah[ks], bh, acc[ct], 0, 0, 0);
                acc[ct] = __builtin_amdgcn_mfma_f32_16x16x32_bf16(ah[ks], bl, acc[ct], 0, 0, 0);
                acc[ct] = __builtin_amdgcn_mfma_f32_16x16x32_bf16(al[ks], bh, acc[ct], 0, 0, 0);
            }
        }

        // stage row-major fp16 16x128 (4KB/wave), then coalesced readout
#pragma unroll
        for (int ct = 0; ct < 8; ++ct) {
            int j = ct * 16 + m;
#pragma unroll
            for (int r = 0; r < 4; ++r)
                st[(quad * 4 + r) * 128 + j] = __half_as_ushort(__float2half(acc[ct][r] + bs[ct]));
        }
        if (pp < 2) {
            // interleaved {k8B,v8B} per 16B group: uint2 slot 2*gg + (0|1)
            int voff = (pp == 1) ? 1 : 0;
#pragma unroll
            for (int t = 0; t < 8; ++t) {
                int flat = t * 64 + lane;                    // 512 uint2 = 16 rows x 32 groups
                int row = flat >> 5, gg = flat & 31;
                kv2[((size_t)(n0 + row)) * 64 + gg * 2 + voff] = st2[flat];
            }
        } else {
#pragma unroll
            for (int t = 0; t < 4; ++t) {
                int flat = t * 64 + lane;                    // 256 uint4 = 16 rows x 16
                qh4[((size_t)(n0 + (flat >> 4))) * 16 + (flat & 15)] = st4[flat];
            }
        }
    }
}

// ---------------- fused per-bucket GAT: LDS CSR + gather + online softmax (R5-measured, 116.6us) ----------------
// Five structural variants (R1/R5/R6/R7/R9) all land 116-121us with FETCH 349MB at ~3.2TB/s
// L2-miss BW: random-gather bandwidth ceiling. This is the best-measured version; frozen.
__global__ __launch_bounds__(256) void gat_bucket(
    const __half* __restrict__ qh, const uint4* __restrict__ kvpack,
    const int* __restrict__ epack, const int* __restrict__ bcur,
    float* __restrict__ out)
{
    __shared__ int hist[32];
    __shared__ int cur[32];
    __shared__ int begs[33];
    __shared__ unsigned short els[CAP];
    int b = blockIdx.x;
    int cnt = min(bcur[b], CAP);
    int base = b * CAP;
    int n0 = b << BSH2;
    int nnodes = min(32, NN - n0);
    int tid = threadIdx.x;

    if (tid < 32) hist[tid] = 0;
    __syncthreads();
    for (int e = tid; e < cnt; e += 256)
        atomicAdd(&hist[epack[base + e] >> 16], 1);
    __syncthreads();
    if (tid < 32) {                        // lanes 0..31 of wave 0: exclusive scan of 32 bins
        int c = hist[tid], inc = c;
#pragma unroll
        for (int d = 1; d < 32; d <<= 1) {
            int t = __shfl_up(inc, d);
            if (tid >= d) inc += t;
        }
        int excl = inc - c;
        begs[tid] = excl;
        cur[tid]  = excl;
        if (tid == 31) begs[32] = excl + c;
    }
    __syncthreads();
    for (int e = tid; e < cnt; e += 256) {
        int p = epack[base + e];
        int pos = atomicAdd(&cur[p >> 16], 1);
        els[pos] = (unsigned short)(p & 0xFFFF);
    }
    __syncthreads();

    int il = tid & 31;
    int hw = tid >> 5;                     // half-wave id: 0..7
    const uint4* kvb = kvpack + il;        // lane-fixed base

    for (int nl = hw; nl < nnodes; nl += 8) {
        int node = n0 + nl;
        int beg = begs[nl], end = begs[nl + 1];

        uint2 qq = *(const uint2*)(qh + (size_t)node * 128 + il * 4);
        h2 qh01 = as_h2(qq.x), qh23 = as_h2(qq.y);

        float m = -INFINITY, ssum = 0.f;
        float o0 = 0.f, o1 = 0.f, o2 = 0.f, o3 = 0.f;

        uint4 kvv[8];
        int nh = end - beg; if (nh > 8) nh = 8;
        if (nh > 0) {
#pragma unroll
            for (int i = 0; i < 8; ++i) {
                int s = els[beg + ((i < nh) ? i : 0)];
                kvv[i] = kvb[(size_t)s * 32];
            }
        }

        for (int j = beg; j < end; j += 8) {
            int jn = j + 8;
            int rem = end - jn;
            uint4 kvn[8];
            if (rem > 0) {                 // prefetch next chunk while computing this one
                int nhc = (rem > 8) ? 8 : rem;
#pragma unroll
                for (int i = 0; i < 8; ++i) {
                    int s = els[jn + ((i < nhc) ? i : 0)];
                    kvn[i] = kvb[(size_t)s * 32];
                }
            }
            float p[8];
#pragma unroll
            for (int i = 0; i < 8; ++i) {
                float t = dot4(as_h2(kvv[i].x), as_h2(kvv[i].y), qh01, qh23);
                t += __shfl_xor(t, 1);
                t += __shfl_xor(t, 2);
                t += __shfl_xor(t, 4);
                p[i] = (i < nh) ? t : -INFINITY;
            }
            float gm = fmaxf(fmaxf(fmaxf(p[0], p[1]), fmaxf(p[2], p[3])),
                             fmaxf(fmaxf(p[4], p[5]), fmaxf(p[6], p[7])));
            float nm = fmaxf(m, gm);
            float nmc = fmaxf(nm, -1e30f);
            float scale = __expf(m - nmc);
            ssum *= scale; o0 *= scale; o1 *= scale; o2 *= scale; o3 *= scale;
#pragma unroll
            for (int i = 0; i < 8; ++i) {
                float w = __expf(p[i] - nmc);
                ssum += w;
                o0 += w * (float)as_h2(kvv[i].z).x;
                o1 += w * (float)as_h2(kvv[i].z).y;
                o2 += w * (float)as_h2(kvv[i].w).x;
                o3 += w * (float)as_h2(kvv[i].w).y;
            }
            m = nm;
#pragma unroll
            for (int i = 0; i < 8; ++i) kvv[i] = kvn[i];
            nh = (rem > 8) ? 8 : rem;
        }

        float invd = (ssum > 0.f) ? 1.f / ssum : 0.f;
        float4 r = {o0 * invd, o1 * invd, o2 * invd, o3 * invd};
        *(float4*)(out + (size_t)node * DD + il * 4) = r;
    }
}

extern "C" void kernel_launch(void* const* d_in, const int* in_sizes, int n_in,
                              void* d_out, int out_size, void* d_ws, size_t ws_size,
                              hipStream_t stream) {
    const float* x  = (const float*)d_in[0];
    const float* Wk = (const float*)d_in[1];
    const float* bk = (const float*)d_in[2];
    const float* Wq = (const float*)d_in[3];
    const float* bq = (const float*)d_in[4];
    const float* Wv = (const float*)d_in[5];
    const float* bv = (const float*)d_in[6];
    const int* src = (const int*)d_in[7];
    const int* dst = (const int*)d_in[8];

    // workspace layout (16B-aligned first)
    uint2*  kv2 = (uint2*)d_ws;                                    // NN*64 uint2: 32x{k8B,v8B}/node
    __half* qh  = (__half*)(kv2 + (size_t)NN * 64);                // NN*DD fp16
    unsigned short* whi = (unsigned short*)(qh + (size_t)NN * DD); // 3*DD*DD
    unsigned short* wlo = whi + (size_t)3 * DD * DD;               // 3*DD*DD
    int* epack = (int*)(wlo + (size_t)3 * DD * DD);                // NBKT2*CAP (padded windows)
    int* bcur  = epack + (size_t)NBKT2 * CAP;                      // NBP2

    hipMemsetAsync(bcur, 0, NBP2 * sizeof(int), stream);
    part_prep<<<NPB + WSB, 256, 0, stream>>>(Wk, Wq, Wv, whi, wlo, src, dst, bcur, epack);
    gemm<<<NGB2, 512, 0, stream>>>(x, whi, wlo, bk, bq, bv, kv2, (uint4*)qh);
    gat_bucket<<<NBKT2, 256, 0, stream>>>(qh, (const uint4*)kv2, epack, bcur, (float*)d_out);
}

// Round 11
// 254.604 us; speedup vs baseline: 1.1665x; 1.1665x over previous
//
#include <hip/hip_runtime.h>
#include <hip/hip_bf16.h>
#include <hip/hip_fp16.h>

#define NN 50000      // nodes
#define NE 1600000    // edges
#define DD 128        // channels
#define HH 4          // heads
#define BSH2 5        // bucket shift: 32 nodes per bucket
#define NBKT2 1563    // ceil(NN / 32)
#define NBP2 2048     // padded bucket count
#define CAP 1408      // padded edges per bucket (mean 1024, +12 sigma)
#define PCHUNK 8192   // edges per partition chunk
#define NPB 196       // ceil(NE / PCHUNK)
#define GGB 316       // gemm-role blocks; GGB + NPB = 512 = exactly 2 blocks/CU co-resident
#define MIDB (GGB + NPB)

typedef __attribute__((ext_vector_type(8))) short short8;
typedef __attribute__((ext_vector_type(4))) float floatx4;
typedef __attribute__((ext_vector_type(2))) _Float16 h2;

__device__ inline h2 as_h2(unsigned u) {
    union { unsigned u; h2 h; } c; c.u = u; return c.h;
}

__device__ inline float dot4(h2 a01, h2 a23, h2 b01, h2 b23) {
#if defined(__has_builtin) && __has_builtin(__builtin_amdgcn_fdot2)
    return __builtin_amdgcn_fdot2(a01, b01, __builtin_amdgcn_fdot2(a23, b23, 0.f, false), false);
#else
    return (float)a01.x * (float)b01.x + (float)a01.y * (float)b01.y +
           (float)a23.x * (float)b23.x + (float)a23.y * (float)b23.y;
#endif
}

// ---------------- prep_w: split fp32 W -> bf16 hi/lo + zero bucket cursors (R0-measured ~4us) ----------------
__global__ __launch_bounds__(256) void prep_w(
    const float* __restrict__ Wk, const float* __restrict__ Wq, const float* __restrict__ Wv,
    unsigned short* __restrict__ hi, unsigned short* __restrict__ lo, int* __restrict__ bcur)
{
    int j = blockIdx.x * 256 + threadIdx.x;
    if (j < NBP2) bcur[j] = 0;
    if (j >= 3 * DD * DD) return;
    int which = j / (DD * DD);
    int off = j - which * (DD * DD);
    const float* W = (which == 0) ? Wk : (which == 1) ? Wq : Wv;
    float w = W[off];
    unsigned int b = __float_as_uint(w);
    unsigned short h = (unsigned short)(b >> 16);
    float hf = __uint_as_float((unsigned int)h << 16);
    float l = w - hf;
    hi[j] = h;
    lo[j] = (unsigned short)(__float_as_uint(l) >> 16);
}

// ---------------- mid: gemm role [0,GGB) CONCURRENT with partition role [GGB,MIDB) ----------------
// 512 blocks at 80KB LDS = exactly 2/CU -> all co-resident from t=0; partition (data-independent
// of gemm: src/dst vs x/W) runs fully under the gemm shadow, and one launch gap (~11us) is saved.
// Gemm role: R7-measured 3-pass (K,V,Q), both hi+lo weights LDS-resident, XOR-swizzled.
// Partition role: R0-measured two-level bucket-window scatter.
__global__ __launch_bounds__(256) void mid(
    const float* __restrict__ x,
    const unsigned short* __restrict__ whi, const unsigned short* __restrict__ wlo,
    const float* __restrict__ bk, const float* __restrict__ bq, const float* __restrict__ bv,
    uint2* __restrict__ kv2, uint4* __restrict__ qh4,
    const int* __restrict__ src, const int* __restrict__ dst,
    int* __restrict__ bcur, int* __restrict__ epack)
{
    __shared__ __align__(16) unsigned char smem[81920];  // gemm: hi|lo|stage; part: h|c2 (16KB)

    if (blockIdx.x < GGB) {
        uint4* wh4 = (uint4*)smem;
        uint4* wl4 = (uint4*)(smem + 32768);
        int tid = threadIdx.x;
        int wave = tid >> 6, lane = tid & 63;
        int m = lane & 15, quad = lane >> 4;
        unsigned short* st = (unsigned short*)(smem + 65536 + wave * 4096);
        uint4* st4 = (uint4*)st;
        uint2* st2 = (uint2*)st;

        for (int pp = 0; pp < 3; ++pp) {
            int wm = (pp == 0) ? 0 : (pp == 1) ? 2 : 1;          // pass order K, V, Q
            const uint4* gh = (const uint4*)whi + (size_t)wm * 2048;
            const uint4* gl = (const uint4*)wlo + (size_t)wm * 2048;
            __syncthreads();                                     // prior pass done reading weights
            for (int g = tid; g < 2048; g += 256) {
                // uint4 g = row*16 + slot; store at slot ^ (row&15)
                int l = (g & ~15) | ((g ^ (g >> 4)) & 15);
                wh4[l] = gh[g];
                wl4[l] = gl[g];
            }
            __syncthreads();
            const float* bias = (pp == 0) ? bk : (pp == 1) ? bv : bq;
            float bs[8];
#pragma unroll
            for (int ct = 0; ct < 8; ++ct) bs[ct] = bias[ct * 16 + m];

            for (int tile = blockIdx.x * 4 + wave; tile < 3125; tile += GGB * 4) {
                int n0 = tile * 16;
                const float* xrow = x + (size_t)(n0 + m) * DD + quad * 8;
                short8 ah[4], al[4];
#pragma unroll
                for (int ks = 0; ks < 4; ++ks) {
                    const float* xr = xrow + ks * 32;
                    float4 t0 = *(const float4*)xr;
                    float4 t1 = *(const float4*)(xr + 4);
                    float xv[8] = {t0.x, t0.y, t0.z, t0.w, t1.x, t1.y, t1.z, t1.w};
#pragma unroll
                    for (int j = 0; j < 8; ++j) {
                        unsigned int b = __float_as_uint(xv[j]);
                        unsigned short h = (unsigned short)(b >> 16);
                        float hf = __uint_as_float((unsigned int)h << 16);
                        float l = xv[j] - hf;
                        ah[ks][j] = (short)h;
                        al[ks][j] = (short)(__float_as_uint(l) >> 16);
                    }
                }

                floatx4 acc[8];
#pragma unroll
                for (int ct = 0; ct < 8; ++ct) acc[ct] = (floatx4){0.f, 0.f, 0.f, 0.f};

#pragma unroll
                for (int ks = 0; ks < 4; ++ks) {
#pragma unroll
                    for (int ct = 0; ct < 8; ++ct) {
                        int r = ct * 16 + m;                     // output channel; r&15 == m
                        int idx = r * 16 + ((ks * 4 + quad) ^ m);
                        short8 bh = ((const short8*)wh4)[idx];
                        short8 bl = ((const short8*)wl4)[idx];
                        acc[ct] = __builtin_amdgcn_mfma_f32_16x16x32_bf16(ah[ks], bh, acc[ct], 0, 0, 0);
                        acc[ct] = __builtin_amdgcn_mfma_f32_16x16x32_bf16(ah[ks], bl, acc[ct], 0, 0, 0);
                        acc[ct] = __builtin_amdgcn_mfma_f32_16x16x32_bf16(al[ks], bh, acc[ct], 0, 0, 0);
                    }
                }

                // stage row-major fp16 16x128 (4KB/wave), then coalesced readout
#pragma unroll
                for (int ct = 0; ct < 8; ++ct) {
                    int j = ct * 16 + m;
#pragma unroll
                    for (int r = 0; r < 4; ++r)
                        st[(quad * 4 + r) * 128 + j] = __half_as_ushort(__float2half(acc[ct][r] + bs[ct]));
                }
                if (pp < 2) {
                    // interleaved {k8B,v8B} per 16B group: uint2 slot 2*gg + (0|1)
                    int voff = (pp == 1) ? 1 : 0;
#pragma unroll
                    for (int t = 0; t < 8; ++t) {
                        int flat = t * 64 + lane;                // 512 uint2 = 16 rows x 32 groups
                        int row = flat >> 5, gg = flat & 31;
                        kv2[((size_t)(n0 + row)) * 64 + gg * 2 + voff] = st2[flat];
                    }
                } else {
#pragma unroll
                    for (int t = 0; t < 4; ++t) {
                        int flat = t * 64 + lane;                // 256 uint4 = 16 rows x 16
                        qh4[((size_t)(n0 + (flat >> 4))) * 16 + (flat & 15)] = st4[flat];
                    }
                }
            }
        }
    } else {
        // ============ PARTITION role: two-level bucket-window scatter (R0-measured) ============
        int* h  = (int*)smem;           // [NBP2]
        int* c2 = h + NBP2;             // [NBP2]
        int pb = blockIdx.x - GGB;
        int b0 = pb * PCHUNK;
        int n = min(PCHUNK, NE - b0);
        for (int i = threadIdx.x; i < NBP2; i += 256) h[i] = 0;
        __syncthreads();
        for (int i = threadIdx.x; i < n; i += 256)
            atomicAdd(&h[dst[b0 + i] >> BSH2], 1);
        __syncthreads();
        for (int i = threadIdx.x; i < NBP2; i += 256)
            c2[i] = h[i] ? i * CAP + atomicAdd(&bcur[i], h[i]) : 0;
        __syncthreads();
        for (int i = threadIdx.x; i < n; i += 256) {
            int d = dst[b0 + i];
            int s = src[b0 + i];
            int bkt = d >> BSH2;
            int pos = atomicAdd(&c2[bkt], 1);
            if (pos < (bkt + 1) * CAP)               // drop-guard (never fires at +12 sigma)
                epack[pos] = ((d & 31) << 16) | s;
        }
    }
}

// ---------------- fused per-bucket GAT: LDS CSR + gather + online softmax (R5-measured, 116.6us) ----------------
// Five structural variants (R1/R5/R6/R7/R9) all land 116-121us with FETCH 349MB at ~3.2TB/s
// miss BW: random-gather bandwidth ceiling. This is the simplest best-measured version; frozen.
__global__ __launch_bounds__(256) void gat_bucket(
    const __half* __restrict__ qh, const uint4* __restrict__ kvpack,
    const int* __restrict__ epack, const int* __restrict__ bcur,
    float* __restrict__ out)
{
    __shared__ int hist[32];
    __shared__ int cur[32];
    __shared__ int begs[33];
    __shared__ unsigned short els[CAP];
    int b = blockIdx.x;
    int cnt = min(bcur[b], CAP);
    int base = b * CAP;
    int n0 = b << BSH2;
    int nnodes = min(32, NN - n0);
    int tid = threadIdx.x;

    if (tid < 32) hist[tid] = 0;
    __syncthreads();
    for (int e = tid; e < cnt; e += 256)
        atomicAdd(&hist[epack[base + e] >> 16], 1);
    __syncthreads();
    if (tid < 32) {                        // lanes 0..31 of wave 0: exclusive scan of 32 bins
        int c = hist[tid], inc = c;
#pragma unroll
        for (int d = 1; d < 32; d <<= 1) {
            int t = __shfl_up(inc, d);
            if (tid >= d) inc += t;
        }
        int excl = inc - c;
        begs[tid] = excl;
        cur[tid]  = excl;
        if (tid == 31) begs[32] = excl + c;
    }
    __syncthreads();
    for (int e = tid; e < cnt; e += 256) {
        int p = epack[base + e];
        int pos = atomicAdd(&cur[p >> 16], 1);
        els[pos] = (unsigned short)(p & 0xFFFF);
    }
    __syncthreads();

    int il = tid & 31;
    int hw = tid >> 5;                     // half-wave id: 0..7
    const uint4* kvb = kvpack + il;        // lane-fixed base

    for (int nl = hw; nl < nnodes; nl += 8) {
        int node = n0 + nl;
        int beg = begs[nl], end = begs[nl + 1];

        uint2 qq = *(const uint2*)(qh + (size_t)node * 128 + il * 4);
        h2 qh01 = as_h2(qq.x), qh23 = as_h2(qq.y);

        float m = -INFINITY, ssum = 0.f;
        float o0 = 0.f, o1 = 0.f, o2 = 0.f, o3 = 0.f;

        uint4 kvv[8];
        int nh = end - beg; if (nh > 8) nh = 8;
        if (nh > 0) {
#pragma unroll
            for (int i = 0; i < 8; ++i) {
                int s = els[beg + ((i < nh) ? i : 0)];
                kvv[i] = kvb[(size_t)s * 32];
            }
        }

        for (int j = beg; j < end; j += 8) {
            int jn = j + 8;
            int rem = end - jn;
            uint4 kvn[8];
            if (rem > 0) {                 // prefetch next chunk while computing this one
                int nhc = (rem > 8) ? 8 : rem;
#pragma unroll
                for (int i = 0; i < 8; ++i) {
                    int s = els[jn + ((i < nhc) ? i : 0)];
                    kvn[i] = kvb[(size_t)s * 32];
                }
            }
            float p[8];
#pragma unroll
            for (int i = 0; i < 8; ++i) {
                float t = dot4(as_h2(kvv[i].x), as_h2(kvv[i].y), qh01, qh23);
                t += __shfl_xor(t, 1);
                t += __shfl_xor(t, 2);
                t += __shfl_xor(t, 4);
                p[i] = (i < nh) ? t : -INFINITY;
            }
            float gm = fmaxf(fmaxf(fmaxf(p[0], p[1]), fmaxf(p[2], p[3])),
                             fmaxf(fmaxf(p[4], p[5]), fmaxf(p[6], p[7])));
            float nm = fmaxf(m, gm);
            float nmc = fmaxf(nm, -1e30f);
            float scale = __expf(m - nmc);
            ssum *= scale; o0 *= scale; o1 *= scale; o2 *= scale; o3 *= scale;
#pragma unroll
            for (int i = 0; i < 8; ++i) {
                float w = __expf(p[i] - nmc);
                ssum += w;
                o0 += w * (float)as_h2(kvv[i].z).x;
                o1 += w * (float)as_h2(kvv[i].z).y;
                o2 += w * (float)as_h2(kvv[i].w).x;
                o3 += w * (float)as_h2(kvv[i].w).y;
            }
            m = nm;
#pragma unroll
            for (int i = 0; i < 8; ++i) kvv[i] = kvn[i];
            nh = (rem > 8) ? 8 : rem;
        }

        float invd = (ssum > 0.f) ? 1.f / ssum : 0.f;
        float4 r = {o0 * invd, o1 * invd, o2 * invd, o3 * invd};
        *(float4*)(out + (size_t)node * DD + il * 4) = r;
    }
}

extern "C" void kernel_launch(void* const* d_in, const int* in_sizes, int n_in,
                              void* d_out, int out_size, void* d_ws, size_t ws_size,
                              hipStream_t stream) {
    const float* x  = (const float*)d_in[0];
    const float* Wk = (const float*)d_in[1];
    const float* bk = (const float*)d_in[2];
    const float* Wq = (const float*)d_in[3];
    const float* bq = (const float*)d_in[4];
    const float* Wv = (const float*)d_in[5];
    const float* bv = (const float*)d_in[6];
    const int* src = (const int*)d_in[7];
    const int* dst = (const int*)d_in[8];

    // workspace layout (16B-aligned first)
    uint2*  kv2 = (uint2*)d_ws;                                    // NN*64 uint2: 32x{k8B,v8B}/node
    __half* qh  = (__half*)(kv2 + (size_t)NN * 64);                // NN*DD fp16
    unsigned short* whi = (unsigned short*)(qh + (size_t)NN * DD); // 3*DD*DD
    unsigned short* wlo = whi + (size_t)3 * DD * DD;               // 3*DD*DD
    int* epack = (int*)(wlo + (size_t)3 * DD * DD);                // NBKT2*CAP (padded windows)
    int* bcur  = epack + (size_t)NBKT2 * CAP;                      // NBP2

    prep_w<<<192, 256, 0, stream>>>(Wk, Wq, Wv, whi, wlo, bcur);
    mid<<<MIDB, 256, 0, stream>>>(x, whi, wlo, bk, bq, bv, kv2, (uint4*)qh,
                                  src, dst, bcur, epack);
    gat_bucket<<<NBKT2, 256, 0, stream>>>(qh, (const uint4*)kv2, epack, bcur, (float*)d_out);
}